// Round 3
// baseline (336.816 us; speedup 1.0000x reference)
//
#include <hip/hip_runtime.h>
#include <hip/hip_bf16.h>

// B=32, S=2048, H=512, fp32 in/out.
// scores = tanh(Y@W + b).w -> softmax(S) -> c_star = alpha@Y
// GEMM: fp16 MFMA, W split hi+lo fp16 (exact W), Y cvt fp32->fp16 in-kernel.
// Double-buffered LDS (48KB), XOR-swizzled -> 0 bank conflicts.
// softmax fused into the weighted-sum kernel (no atomics, no memsets).

#define Bsz 32
#define Ssz 2048
#define Hsz 512
#define Msz (Bsz * Ssz)   // 65536

using half8   = __attribute__((ext_vector_type(8))) _Float16;
using floatx4 = __attribute__((ext_vector_type(4))) float;

__device__ __forceinline__ void llds(_Float16* l, const _Float16* g) {
  __builtin_amdgcn_global_load_lds((const __attribute__((address_space(1))) void*)g,
                                   (__attribute__((address_space(3))) void*)l, 16, 0, 0);
}

__device__ __forceinline__ float fast_tanh(float x) {
  const float e = __expf(2.f * x);
  return 1.f - 2.f / (e + 1.f);
}

// ---- W[k][n] -> Wt[n][k'] fp16: k'<512 hi, k'>=512 lo residual ----
__global__ __launch_bounds__(256) void wsplit_k(const float* __restrict__ W,
                                                _Float16* __restrict__ Wt) {
  __shared__ float tile[32][33];
  const int bx = blockIdx.x & 15, by = blockIdx.x >> 4;
  const int tx = threadIdx.x & 31, ty = threadIdx.x >> 5;
#pragma unroll
  for (int i = 0; i < 4; ++i)
    tile[ty + 8 * i][tx] = W[(size_t)(by * 32 + ty + 8 * i) * Hsz + bx * 32 + tx];
  __syncthreads();
#pragma unroll
  for (int i = 0; i < 4; ++i) {
    const int n = bx * 32 + ty + 8 * i;
    const int k = by * 32 + tx;
    const float v = tile[tx][ty + 8 * i];
    const _Float16 hi = (_Float16)v;
    const _Float16 lo = (_Float16)(v - (float)hi);
    Wt[(size_t)n * 1024 + k] = hi;
    Wt[(size_t)n * 1024 + 512 + k] = lo;
  }
}

// ---- GEMM (double-buffered) + tanh.w partial-score epilogue ----
__global__ __launch_bounds__(256) void gemm_score_k(const float* __restrict__ Y,
                                                    const _Float16* __restrict__ Wt,
                                                    const float* __restrict__ bvec,
                                                    const float* __restrict__ wvec,
                                                    float* __restrict__ scores4) {
  __shared__ __align__(16) _Float16 As[2][128 * 32];
  __shared__ __align__(16) _Float16 Bh[2][128 * 32];
  __shared__ __align__(16) _Float16 Bl[2][128 * 32];
  const int tid = threadIdx.x;
  const int lane = tid & 63, wv = tid >> 6;
  const int wr = wv >> 1, wc = wv & 1;
  const int lr = lane & 15, lq = lane >> 4;
  // XCD-aware decode: 4 n-siblings of one mblk share (g&7) -> same XCD L2.
  const int g = blockIdx.x;
  const int x = g & 7, q = g >> 3;
  const int nblk = q & 3;
  const int mblk = (q >> 2) * 8 + x;

  floatx4 acc[4][4];
#pragma unroll
  for (int rf = 0; rf < 4; ++rf)
#pragma unroll
    for (int cf = 0; cf < 4; ++cf)
      acc[rf][cf] = (floatx4){0.f, 0.f, 0.f, 0.f};

  // A staging (thread-constant): 16 contiguous floats per thread per tile
  const int arow = tid >> 1;
  const int p0 = (tid & 1) * 2;
  const float* aga = Y + ((size_t)(mblk * 128 + arow)) * Hsz + p0 * 8;
  const int s0 = (p0 ^ ((arow >> 1) & 3)) * 8;
  const int s1 = ((p0 + 1) ^ ((arow >> 1) & 3)) * 8;
  const size_t brow0 = (size_t)nblk * 128 * 1024;

  // B async stage for tile it into buffer buf
  auto stageB = [&](int it, int buf) {
    const int k0 = it * 32;
#pragma unroll
    for (int i = 0; i < 2; ++i) {
      const int cbase = i * 256 + wv * 64;
      const int c = cbase + lane;
      const int brow = c >> 2;
      const int gpart = (c & 3) ^ ((c >> 3) & 3);
      const _Float16* gb = Wt + brow0 + (size_t)brow * 1024 + (k0 + gpart * 8);
      llds(&Bh[buf][cbase * 8], gb);
      llds(&Bl[buf][cbase * 8], gb + 512);
    }
  };
  auto loadA = [&](int it, float4* f) {
    const float4* g4 = (const float4*)(aga + it * 32);
    f[0] = g4[0]; f[1] = g4[1]; f[2] = g4[2]; f[3] = g4[3];
  };
  auto cvtWriteA = [&](const float4* f, int buf) {
    half8 h0, h1;
    h0[0] = (_Float16)f[0].x; h0[1] = (_Float16)f[0].y; h0[2] = (_Float16)f[0].z; h0[3] = (_Float16)f[0].w;
    h0[4] = (_Float16)f[1].x; h0[5] = (_Float16)f[1].y; h0[6] = (_Float16)f[1].z; h0[7] = (_Float16)f[1].w;
    h1[0] = (_Float16)f[2].x; h1[1] = (_Float16)f[2].y; h1[2] = (_Float16)f[2].z; h1[3] = (_Float16)f[2].w;
    h1[4] = (_Float16)f[3].x; h1[5] = (_Float16)f[3].y; h1[6] = (_Float16)f[3].z; h1[7] = (_Float16)f[3].w;
    *(half8*)&As[buf][arow * 32 + s0] = h0;
    *(half8*)&As[buf][arow * 32 + s1] = h1;
  };

  // prologue: tile 0 -> buf 0
  {
    float4 fa[4];
    stageB(0, 0);
    loadA(0, fa);
    cvtWriteA(fa, 0);
    __syncthreads();
  }

  for (int it = 0; it < 16; ++it) {
    const int p = it & 1;
    float4 fb[4];
    if (it < 15) {
      stageB(it + 1, p ^ 1);   // async llds, lands by next barrier
      loadA(it + 1, fb);       // to VGPR; waited only at cvtWriteA below
    }

    half8 a[4], bhf[4], blf[4];
#pragma unroll
    for (int rf = 0; rf < 4; ++rf) {
      const int ar = wr * 64 + rf * 16 + lr;
      a[rf] = *(const half8*)&As[p][ar * 32 + (lq ^ ((ar >> 1) & 3)) * 8];
    }
#pragma unroll
    for (int cf = 0; cf < 4; ++cf) {
      const int nr = wc * 64 + cf * 16 + lr;
      const int na = nr * 32 + (lq ^ ((nr >> 1) & 3)) * 8;
      bhf[cf] = *(const half8*)&Bh[p][na];
      blf[cf] = *(const half8*)&Bl[p][na];
    }
#pragma unroll
    for (int rf = 0; rf < 4; ++rf)
#pragma unroll
      for (int cf = 0; cf < 4; ++cf)
        acc[rf][cf] = __builtin_amdgcn_mfma_f32_16x16x32_f16(a[rf], bhf[cf], acc[rf][cf], 0, 0, 0);
#pragma unroll
    for (int rf = 0; rf < 4; ++rf)
#pragma unroll
      for (int cf = 0; cf < 4; ++cf)
        acc[rf][cf] = __builtin_amdgcn_mfma_f32_16x16x32_f16(a[rf], blf[cf], acc[rf][cf], 0, 0, 0);

    if (it < 15)
      cvtWriteA(fb, p ^ 1);    // vmcnt wait lands here, after MFMAs
    __syncthreads();
  }

  // Epilogue: v = sum_cols tanh(pre+b)*w; 16-lane shuffle reduce;
  // combine 2 col-waves via LDS; non-atomic per-nblk partial store.
  float bb[4], ww[4];
  const int colbase = nblk * 128 + wc * 64;
#pragma unroll
  for (int cf = 0; cf < 4; ++cf) {
    const int col = colbase + cf * 16 + lr;
    bb[cf] = bvec[col];
    ww[cf] = wvec[col];
  }
  float* red = (float*)As;  // 256 floats, reuse LDS
#pragma unroll
  for (int rf = 0; rf < 4; ++rf) {
#pragma unroll
    for (int r = 0; r < 4; ++r) {
      float v = 0.f;
#pragma unroll
      for (int cf = 0; cf < 4; ++cf)
        v += fast_tanh(acc[rf][cf][r] + bb[cf]) * ww[cf];
      v += __shfl_xor(v, 1, 16);
      v += __shfl_xor(v, 2, 16);
      v += __shfl_xor(v, 4, 16);
      v += __shfl_xor(v, 8, 16);
      if (lr == 0)
        red[(wr * 64 + rf * 16 + lq * 4 + r) * 2 + wc] = v;
    }
  }
  __syncthreads();
  if (tid < 128)
    scores4[(size_t)nblk * Msz + mblk * 128 + tid] = red[2 * tid] + red[2 * tid + 1];
}

// ---- fused softmax + c_star: one block per (b, 64-wide h-slice) ----
__global__ __launch_bounds__(256) void wsum_fused_k(const float* __restrict__ scores4,
                                                    const float* __restrict__ mask,
                                                    const float* __restrict__ Y,
                                                    float* __restrict__ out) {
  const int b = blockIdx.x >> 3, hs = blockIdx.x & 7;
  const int t = threadIdx.x, lane = t & 63, wv = t >> 6;
  __shared__ float alpha_s[Ssz];   // 8 KB
  __shared__ float rbuf[256];
  __shared__ float rm[4], rs[4];

  float s[8];
  float mx = -3.4e38f;
#pragma unroll
  for (int i = 0; i < 8; ++i) {
    const int idx = b * Ssz + i * 256 + t;
    float v = scores4[idx] + scores4[Msz + idx] + scores4[2 * Msz + idx] + scores4[3 * Msz + idx];
    v -= 1000.f * (1.f - mask[idx]);
    s[i] = v;
    mx = fmaxf(mx, v);
  }
  for (int off = 32; off > 0; off >>= 1) mx = fmaxf(mx, __shfl_xor(mx, off, 64));
  if (lane == 0) rm[wv] = mx;
  __syncthreads();
  mx = fmaxf(fmaxf(rm[0], rm[1]), fmaxf(rm[2], rm[3]));
  float sum = 0.f;
#pragma unroll
  for (int i = 0; i < 8; ++i) {
    s[i] = __expf(s[i] - mx);
    sum += s[i];
  }
  for (int off = 32; off > 0; off >>= 1) sum += __shfl_xor(sum, off, 64);
  if (lane == 0) rs[wv] = sum;
  __syncthreads();
  sum = rs[0] + rs[1] + rs[2] + rs[3];
  const float inv = 1.f / sum;
#pragma unroll
  for (int i = 0; i < 8; ++i) alpha_s[i * 256 + t] = s[i] * inv;
  __syncthreads();

  // weighted sum: wave wv handles s in [wv*512, wv*512+512); lane = h offset
  const float* Yp = Y + (size_t)b * Ssz * Hsz + hs * 64 + lane;
  const int sbase = wv * 512;
  float acc = 0.f;
#pragma unroll 8
  for (int k = 0; k < 512; ++k)
    acc = fmaf(alpha_s[sbase + k], Yp[(size_t)(sbase + k) * Hsz], acc);
  rbuf[t] = acc;
  __syncthreads();
  if (wv == 0)
    out[b * Hsz + hs * 64 + lane] =
        rbuf[lane] + rbuf[64 + lane] + rbuf[128 + lane] + rbuf[192 + lane];
}

extern "C" void kernel_launch(void* const* d_in, const int* in_sizes, int n_in,
                              void* d_out, int out_size, void* d_ws, size_t ws_size,
                              hipStream_t stream) {
  (void)in_sizes; (void)n_in; (void)out_size; (void)ws_size;
  const float* Y    = (const float*)d_in[0];
  const float* mask = (const float*)d_in[1];
  const float* W    = (const float*)d_in[2];
  const float* bvec = (const float*)d_in[3];
  const float* wvec = (const float*)d_in[4];
  float* out = (float*)d_out;

  char* ws = (char*)d_ws;
  _Float16* Wt   = (_Float16*)ws;                        // 1 MB
  float* scores4 = (float*)(ws + ((size_t)1 << 20));     // 1 MB (4 partials)

  wsplit_k<<<256, 256, 0, stream>>>(W, Wt);
  gemm_score_k<<<(Msz / 128) * 4, 256, 0, stream>>>(Y, Wt, bvec, wvec, scores4);
  wsum_fused_k<<<Bsz * 8, 256, 0, stream>>>(scores4, mask, Y, out);
}

// Round 4
// 274.376 us; speedup vs baseline: 1.2276x; 1.2276x over previous
//
#include <hip/hip_runtime.h>
#include <hip/hip_bf16.h>

// B=32, S=2048, H=512, fp32 in/out.
// scores = tanh(Y@W + b).w -> softmax(S) -> c_star = alpha@Y
// GEMM: single fp16 MFMA (W fp16 RNE; error budget ~0.044 < 0.078 thr),
// single-buffered 16KB LDS, XOR-swizzled (0 conflicts), fused Y cvt.
// c_star: two-stage atomic-free reduction streaming contiguous 128KB/block.

#define Bsz 32
#define Ssz 2048
#define Hsz 512
#define Msz (Bsz * Ssz)   // 65536

using half8   = __attribute__((ext_vector_type(8))) _Float16;
using floatx4 = __attribute__((ext_vector_type(4))) float;

__device__ __forceinline__ void llds(_Float16* l, const _Float16* g) {
  __builtin_amdgcn_global_load_lds((const __attribute__((address_space(1))) void*)g,
                                   (__attribute__((address_space(3))) void*)l, 16, 0, 0);
}

__device__ __forceinline__ float fast_tanh(float x) {
  const float e = __expf(2.f * x);
  return 1.f - 2.f / (e + 1.f);
}

// ---- W[k][n] fp32 -> Wt[n][k] fp16 (transpose + RNE cast) ----
__global__ __launch_bounds__(256) void wsplit_k(const float* __restrict__ W,
                                                _Float16* __restrict__ Wt) {
  __shared__ float tile[32][33];
  const int bx = blockIdx.x & 15, by = blockIdx.x >> 4;
  const int tx = threadIdx.x & 31, ty = threadIdx.x >> 5;
#pragma unroll
  for (int i = 0; i < 4; ++i)
    tile[ty + 8 * i][tx] = W[(size_t)(by * 32 + ty + 8 * i) * Hsz + bx * 32 + tx];
  __syncthreads();
#pragma unroll
  for (int i = 0; i < 4; ++i) {
    const int n = bx * 32 + ty + 8 * i;
    const int k = by * 32 + tx;
    Wt[(size_t)n * Hsz + k] = (_Float16)tile[tx][ty + 8 * i];
  }
}

// ---- GEMM (single-buffer, fused Y cvt) + tanh.w partial-score epilogue ----
__global__ __launch_bounds__(256) void gemm_score_k(const float* __restrict__ Y,
                                                    const _Float16* __restrict__ Wt,
                                                    const float* __restrict__ bvec,
                                                    const float* __restrict__ wvec,
                                                    float* __restrict__ scores4) {
  __shared__ __align__(16) _Float16 As[128 * 32];
  __shared__ __align__(16) _Float16 Bh[128 * 32];
  const int tid = threadIdx.x;
  const int lane = tid & 63, wv = tid >> 6;
  const int wr = wv >> 1, wc = wv & 1;
  const int lr = lane & 15, lq = lane >> 4;
  // XCD-aware decode: 4 n-siblings of one mblk share (g&7) -> same XCD L2.
  const int g = blockIdx.x;
  const int x = g & 7, q = g >> 3;
  const int nblk = q & 3;
  const int mblk = (q >> 2) * 8 + x;

  floatx4 acc[4][4];
#pragma unroll
  for (int rf = 0; rf < 4; ++rf)
#pragma unroll
    for (int cf = 0; cf < 4; ++cf)
      acc[rf][cf] = (floatx4){0.f, 0.f, 0.f, 0.f};

  // A staging (thread-constant): 16 contiguous floats per thread per tile
  const int arow = tid >> 1;
  const int p0 = (tid & 1) * 2;
  const float* aga = Y + ((size_t)(mblk * 128 + arow)) * Hsz + p0 * 8;
  const int s0 = (p0 ^ ((arow >> 1) & 3)) * 8;
  const int s1 = ((p0 + 1) ^ ((arow >> 1) & 3)) * 8;
  const size_t brow0 = (size_t)nblk * 128 * Hsz;

  // B llds staging (thread-constant parts)
  const int bc = wv * 64 + lane;              // chunk id 0..255 (first half)
  const int brow_a = bc >> 1;                 // rows 0..127, 2 chunks/row? no:
  // 8KB tile = 512 chunks of 16B; 256 lanes -> 2 llds each
  for (int it = 0; it < 16; ++it) {
    const int k0 = it * 32;
#pragma unroll
    for (int i = 0; i < 2; ++i) {
      const int c = i * 256 + wv * 64 + lane;
      const int brow = c >> 2;
      const int gpart = (c & 3) ^ ((c >> 3) & 3);
      llds(&Bh[(i * 256 + wv * 64) * 8],
           Wt + brow0 + (size_t)brow * Hsz + (k0 + gpart * 8));
    }
    {
      const float4* g4 = (const float4*)(aga + k0);
      const float4 f0 = g4[0], f1 = g4[1], f2 = g4[2], f3 = g4[3];
      half8 h0, h1;
      h0[0] = (_Float16)f0.x; h0[1] = (_Float16)f0.y; h0[2] = (_Float16)f0.z; h0[3] = (_Float16)f0.w;
      h0[4] = (_Float16)f1.x; h0[5] = (_Float16)f1.y; h0[6] = (_Float16)f1.z; h0[7] = (_Float16)f1.w;
      h1[0] = (_Float16)f2.x; h1[1] = (_Float16)f2.y; h1[2] = (_Float16)f2.z; h1[3] = (_Float16)f2.w;
      h1[4] = (_Float16)f3.x; h1[5] = (_Float16)f3.y; h1[6] = (_Float16)f3.z; h1[7] = (_Float16)f3.w;
      *(half8*)&As[arow * 32 + s0] = h0;
      *(half8*)&As[arow * 32 + s1] = h1;
    }
    __syncthreads();

    half8 a[4], bhf[4];
#pragma unroll
    for (int rf = 0; rf < 4; ++rf) {
      const int ar = wr * 64 + rf * 16 + lr;
      a[rf] = *(const half8*)&As[ar * 32 + (lq ^ ((ar >> 1) & 3)) * 8];
    }
#pragma unroll
    for (int cf = 0; cf < 4; ++cf) {
      const int nr = wc * 64 + cf * 16 + lr;
      bhf[cf] = *(const half8*)&Bh[nr * 32 + (lq ^ ((nr >> 1) & 3)) * 8];
    }
#pragma unroll
    for (int rf = 0; rf < 4; ++rf)
#pragma unroll
      for (int cf = 0; cf < 4; ++cf)
        acc[rf][cf] = __builtin_amdgcn_mfma_f32_16x16x32_f16(a[rf], bhf[cf], acc[rf][cf], 0, 0, 0);
    __syncthreads();
  }

  // Epilogue: v = sum_cols tanh(pre+b)*w; 16-lane shuffle reduce;
  // combine 2 col-waves via LDS; non-atomic per-nblk partial store.
  float bb[4], ww[4];
  const int colbase = nblk * 128 + wc * 64;
#pragma unroll
  for (int cf = 0; cf < 4; ++cf) {
    const int col = colbase + cf * 16 + lr;
    bb[cf] = bvec[col];
    ww[cf] = wvec[col];
  }
  float* red = (float*)As;  // 256 floats, reuse LDS
#pragma unroll
  for (int rf = 0; rf < 4; ++rf) {
#pragma unroll
    for (int r = 0; r < 4; ++r) {
      float v = 0.f;
#pragma unroll
      for (int cf = 0; cf < 4; ++cf)
        v += fast_tanh(acc[rf][cf][r] + bb[cf]) * ww[cf];
      v += __shfl_xor(v, 1, 16);
      v += __shfl_xor(v, 2, 16);
      v += __shfl_xor(v, 4, 16);
      v += __shfl_xor(v, 8, 16);
      if (lr == 0)
        red[(wr * 64 + rf * 16 + lq * 4 + r) * 2 + wc] = v;
    }
  }
  __syncthreads();
  if (tid < 128)
    scores4[(size_t)nblk * Msz + mblk * 128 + tid] = red[2 * tid] + red[2 * tid + 1];
}

// ---- softmax over S, summing 4 nblk partials -> alpha ----
__global__ __launch_bounds__(256) void softmax_k(const float* __restrict__ scores4,
                                                 const float* __restrict__ mask,
                                                 float* __restrict__ alpha) {
  const int b = blockIdx.x, t = threadIdx.x;
  const int lane = t & 63, wv = t >> 6;
  float s[8];
  float mx = -3.4e38f;
#pragma unroll
  for (int i = 0; i < 8; ++i) {
    const int idx = b * Ssz + i * 256 + t;
    float v = scores4[idx] + scores4[Msz + idx] + scores4[2 * Msz + idx] + scores4[3 * Msz + idx];
    v -= 1000.f * (1.f - mask[idx]);
    s[i] = v;
    mx = fmaxf(mx, v);
  }
  for (int off = 32; off > 0; off >>= 1) mx = fmaxf(mx, __shfl_xor(mx, off, 64));
  __shared__ float rm[4], rs[4];
  if (lane == 0) rm[wv] = mx;
  __syncthreads();
  mx = fmaxf(fmaxf(rm[0], rm[1]), fmaxf(rm[2], rm[3]));
  float sum = 0.f;
#pragma unroll
  for (int i = 0; i < 8; ++i) {
    s[i] = __expf(s[i] - mx);
    sum += s[i];
  }
  for (int off = 32; off > 0; off >>= 1) sum += __shfl_xor(sum, off, 64);
  if (lane == 0) rs[wv] = sum;
  __syncthreads();
  sum = rs[0] + rs[1] + rs[2] + rs[3];
  const float inv = 1.f / sum;
#pragma unroll
  for (int i = 0; i < 8; ++i) alpha[b * Ssz + i * 256 + t] = s[i] * inv;
}

// ---- stage 1: partial[b][sc][h] = sum over 64 consecutive s of alpha*Y ----
// block = (b, sc): streams a CONTIGUOUS 128KB slab of Y. Wave wv: rows
// s0+wv*16..+16; lane holds h = lane*8..+8 (two float4 per row).
__global__ __launch_bounds__(256) void wsum1_k(const float* __restrict__ alpha,
                                               const float* __restrict__ Y,
                                               float* __restrict__ partial) {
  const int b = blockIdx.x >> 5, sc = blockIdx.x & 31;
  const int t = threadIdx.x, lane = t & 63, wv = t >> 6;
  __shared__ float part[4 * 512];
  const int s0 = sc * 64 + wv * 16;
  const float* al = alpha + b * Ssz + s0;
  const float4* Yb = (const float4*)(Y + ((size_t)b * Ssz + s0) * Hsz);
  float a0 = 0.f, a1 = 0.f, a2 = 0.f, a3 = 0.f, a4 = 0.f, a5 = 0.f, a6 = 0.f, a7 = 0.f;
#pragma unroll 4
  for (int r = 0; r < 16; ++r) {
    const float a = al[r];
    const float4 y0 = Yb[r * 128 + lane * 2];
    const float4 y1 = Yb[r * 128 + lane * 2 + 1];
    a0 = fmaf(a, y0.x, a0); a1 = fmaf(a, y0.y, a1);
    a2 = fmaf(a, y0.z, a2); a3 = fmaf(a, y0.w, a3);
    a4 = fmaf(a, y1.x, a4); a5 = fmaf(a, y1.y, a5);
    a6 = fmaf(a, y1.z, a6); a7 = fmaf(a, y1.w, a7);
  }
  // transposed store (value for h=lane*8+j at idx j*64+lane): conflict-free
  part[wv * 512 + 0 * 64 + lane] = a0;
  part[wv * 512 + 1 * 64 + lane] = a1;
  part[wv * 512 + 2 * 64 + lane] = a2;
  part[wv * 512 + 3 * 64 + lane] = a3;
  part[wv * 512 + 4 * 64 + lane] = a4;
  part[wv * 512 + 5 * 64 + lane] = a5;
  part[wv * 512 + 6 * 64 + lane] = a6;
  part[wv * 512 + 7 * 64 + lane] = a7;
  __syncthreads();
#pragma unroll
  for (int i = 0; i < 2; ++i) {
    const int h = i * 256 + t;
    const int idx = (h & 7) * 64 + (h >> 3);
    partial[((size_t)(b * 32 + sc)) * Hsz + h] =
        part[idx] + part[512 + idx] + part[1024 + idx] + part[1536 + idx];
  }
}

// ---- stage 2: out[b][h] = sum over 32 sc of partial ----
__global__ __launch_bounds__(256) void wsum2_k(const float* __restrict__ partial,
                                               float* __restrict__ out) {
  const int b = blockIdx.x >> 1;
  const int h = (blockIdx.x & 1) * 256 + threadIdx.x;
  float s = 0.f;
#pragma unroll 8
  for (int sc = 0; sc < 32; ++sc)
    s += partial[((size_t)(b * 32 + sc)) * Hsz + h];
  out[b * Hsz + h] = s;
}

extern "C" void kernel_launch(void* const* d_in, const int* in_sizes, int n_in,
                              void* d_out, int out_size, void* d_ws, size_t ws_size,
                              hipStream_t stream) {
  (void)in_sizes; (void)n_in; (void)out_size; (void)ws_size;
  const float* Y    = (const float*)d_in[0];
  const float* mask = (const float*)d_in[1];
  const float* W    = (const float*)d_in[2];
  const float* bvec = (const float*)d_in[3];
  const float* wvec = (const float*)d_in[4];
  float* out = (float*)d_out;

  char* ws = (char*)d_ws;
  _Float16* Wt   = (_Float16*)ws;                            // 512 KB
  float* scores4 = (float*)(ws + ((size_t)1 << 20));         // 1 MB
  float* alpha   = (float*)(ws + ((size_t)2 << 20));         // 256 KB
  float* partial = (float*)(ws + ((size_t)2 << 20) + (512u << 10)); // 2 MB

  wsplit_k<<<256, 256, 0, stream>>>(W, Wt);
  gemm_score_k<<<(Msz / 128) * 4, 256, 0, stream>>>(Y, Wt, bvec, wvec, scores4);
  softmax_k<<<Bsz, 256, 0, stream>>>(scores4, mask, alpha);
  wsum1_k<<<Bsz * 32, 256, 0, stream>>>(alpha, Y, partial);
  wsum2_k<<<Bsz * 2, 256, 0, stream>>>(partial, out);
}